// Round 5
// baseline (1765.124 us; speedup 1.0000x reference)
//
#include <hip/hip_runtime.h>
#include <hip/hip_fp16.h>

#define NUM_USERS 100000
#define NUM_ITEMS 50000
#define EMBED_DIM 64
#define N_NODES 150000
#define N_EDGES 4000000
#define N_LAYERS 3
#define BATCH 1024

#define NBKT2 1024          // buckets: bucket = n & 1023, local = n >> 10 (0..146)
#define NROW_B 147          // max locals per bucket
#define CHUNK 8192
#define NBLK_A ((N_EDGES + CHUNK - 1) / CHUNK)   // 489

#define NSLICE 10           // dst slice = dst >> 14 (2 MB fp16 table per slice)
#define NKEY2 2560          // passB key = local<<4 | slice  (max 146*16+9 = 2345)

#define GBLK2 1024          // persistent gather grid: exactly 4 blocks/CU

typedef float f32x4 __attribute__((ext_vector_type(4)));
typedef _Float16 f16x8 __attribute__((ext_vector_type(8)));
typedef float f32x4a __attribute__((ext_vector_type(4)));

// clear uflag + barrier counters
__global__ void clear_uflag_kernel(int* __restrict__ uflag, int* __restrict__ bar) {
    int i = blockIdx.x * blockDim.x + threadIdx.x;
    if (i < NUM_USERS) uflag[i] = 0;
    if (i < 64) bar[i] = 0;
}

__global__ void mark_users_kernel(const int* __restrict__ users, int* __restrict__ uflag) {
    int i = blockIdx.x * blockDim.x + threadIdx.x;
    if (i < BATCH) uflag[users[i]] = 1;
}

// ---------------- init: fp16 table (all) + acc fp32 (needed rows only) -------
__global__ void init_emb_kernel(const float* __restrict__ ue, const float* __restrict__ ie,
                                const int* __restrict__ uflag,
                                float* __restrict__ acc, __half2* __restrict__ h0) {
    int i = blockIdx.x * blockDim.x + threadIdx.x;           // float4 index
    const int total  = N_NODES * (EMBED_DIM / 4);
    const int usplit = NUM_USERS * (EMBED_DIM / 4);
    if (i < total) {
        float4 v = (i < usplit) ? reinterpret_cast<const float4*>(ue)[i]
                                : reinterpret_cast<const float4*>(ie)[i - usplit];
        h0[i * 2 + 0] = __float22half2_rn(make_float2(v.x, v.y));
        h0[i * 2 + 1] = __float22half2_rn(make_float2(v.z, v.w));
        int n = i >> 4;
        if (n >= NUM_USERS || uflag[n])
            reinterpret_cast<float4*>(acc)[i] = v;
    }
}

// ---------------- CSR build: two-level LDS counting sort (NO global atomics) -
__global__ void histA_kernel(const int* __restrict__ src, int* __restrict__ hist) {
    __shared__ int lcnt[NBKT2];
    int blk = blockIdx.x, t = threadIdx.x;
    for (int b = t; b < NBKT2; b += 256) lcnt[b] = 0;
    __syncthreads();
    int e0 = blk * CHUNK;
    for (int i = t; i < CHUNK; i += 256) {
        int e = e0 + i;
        if (e < N_EDGES) atomicAdd(&lcnt[src[e] & 1023], 1);
    }
    __syncthreads();
    for (int b = t; b < NBKT2; b += 256) hist[blk * NBKT2 + b] = lcnt[b];
}

__global__ void scanA_kernel(const int* __restrict__ hist, int* __restrict__ off,
                             int* __restrict__ bucketTotal) {
    __shared__ int s[512];
    int b = blockIdx.x, t = threadIdx.x;         // 512 threads, grid = 1024
    int v0 = (t < NBLK_A) ? hist[t * NBKT2 + b] : 0;
    s[t] = v0;
    __syncthreads();
    for (int o = 1; o < 512; o <<= 1) {
        int v = (t >= o) ? s[t - o] : 0;
        __syncthreads();
        s[t] += v;
        __syncthreads();
    }
    if (t < NBLK_A) off[t * NBKT2 + b] = s[t] - v0;   // exclusive
    if (t == NBLK_A - 1) bucketTotal[b] = s[t];
}

// scan of 1024 bucket totals with 512 threads (2 elements each)
__global__ void scanB2_kernel(const int* __restrict__ bucketTotal, int* __restrict__ bucketBase) {
    __shared__ int s[512];
    int t = threadIdx.x;                         // 512 threads
    int a0 = bucketTotal[2 * t], a1 = bucketTotal[2 * t + 1];
    s[t] = a0 + a1;
    __syncthreads();
    for (int o = 1; o < 512; o <<= 1) {
        int v = (t >= o) ? s[t - o] : 0;
        __syncthreads();
        s[t] += v;
        __syncthreads();
    }
    int excl = s[t] - (a0 + a1);
    bucketBase[2 * t]     = excl;
    bucketBase[2 * t + 1] = excl + a0;
    if (t == 511) bucketBase[1024] = s[511];
}

// A3: partition edges to bucket segments. tmp = (local, dst|q14<<18)
__global__ void partA3_kernel(const int* __restrict__ src, const int* __restrict__ dst,
                              const float* __restrict__ val, const int* __restrict__ off,
                              const int* __restrict__ bucketBase, int2* __restrict__ tmp) {
    __shared__ int lcnt[NBKT2];
    int blk = blockIdx.x, t = threadIdx.x;
    for (int b = t; b < NBKT2; b += 256) lcnt[b] = 0;
    __syncthreads();
    int e0 = blk * CHUNK;
    for (int i = t; i < CHUNK; i += 256) {
        int e = e0 + i;
        if (e < N_EDGES) {
            int s = src[e];
            int b = s & 1023;
            int r = atomicAdd(&lcnt[b], 1);
            int pos = bucketBase[b] + off[blk * NBKT2 + b] + r;
            int q = (int)(val[e] * 16384.0f);
            if (q > 16383) q = 16383;
            tmp[pos] = make_int2(s >> 10, dst[e] | (q << 18));
        }
    }
}

// B: per bucket counting sort by key = local<<4 | slice (LOCAL-MAJOR: each
// row's edges contiguous, internally slice-segmented). Emits 4B edge records
// (dst|q14<<18) plus sliceptr (11 ints per row).
// R4 bug was slice-major keying here while the gather assumed local-major.
__global__ __launch_bounds__(512)
void passB2_kernel(const int2* __restrict__ tmp, const int* __restrict__ bucketBase,
                   int* __restrict__ slp, unsigned* __restrict__ edge_s) {
    __shared__ int sdeg[NKEY2];
    __shared__ int cur[NKEY2];
    __shared__ int ttot[512];
    int bkt = blockIdx.x;
    int t = threadIdx.x;                         // 512 threads
    int base = bucketBase[bkt];
    int cntE = bucketBase[bkt + 1] - base;
    for (int k = t; k < NKEY2; k += 512) sdeg[k] = 0;
    __syncthreads();
    for (int i = t; i < cntE; i += 512) {
        int2 e = tmp[base + i];
        int key = (e.x << 4) | ((e.y & 0x3FFFF) >> 14);
        atomicAdd(&sdeg[key], 1);
    }
    __syncthreads();
    int run = 0;
    int k0 = t * 5;                              // 512*5 = 2560 keys
#pragma unroll
    for (int i = 0; i < 5; ++i) { int v = sdeg[k0 + i]; sdeg[k0 + i] = run; run += v; }
    ttot[t] = run;
    __syncthreads();
    for (int o = 1; o < 512; o <<= 1) {
        int v = (t >= o) ? ttot[t - o] : 0;
        __syncthreads();
        ttot[t] += v;
        __syncthreads();
    }
    int texcl = ttot[t] - run;
#pragma unroll
    for (int i = 0; i < 5; ++i) { int v = sdeg[k0 + i] + texcl; sdeg[k0 + i] = v; cur[k0 + i] = v; }
    __syncthreads();
    // sliceptr emission: thread t = local row index. Row t's edges occupy
    // [sdeg[t<<4|0], sdeg[(t+1)<<4]) with slice-sl segment starting at
    // sdeg[t<<4|sl]  (keys t<<4|10..15 have zero count -> same as (t+1)<<4).
    if (t < NROW_B) {
        int n = t * 1024 + bkt;
        if (n < N_NODES) {
            int rb = n * 11;
#pragma unroll
            for (int sl = 0; sl < NSLICE; ++sl) slp[rb + sl] = base + sdeg[(t << 4) | sl];
            slp[rb + NSLICE] = base + sdeg[(t + 1) << 4];
        }
    }
    for (int i = t; i < cntE; i += 512) {
        int2 e = tmp[base + i];
        int key = (e.x << 4) | ((e.y & 0x3FFFF) >> 14);
        int p = base + atomicAdd(&cur[key], 1);
        edge_s[p] = (unsigned)e.y;
    }
}

// ---------------- propagation: persistent slice-synced deep-ILP gather -------
#define ACCP(P, R, V)                                                           \
    {                                                                           \
        const __half2* hp = reinterpret_cast<const __half2*>(&(R));             \
        float2 f0 = __half22float2(hp[0]); float2 f1 = __half22float2(hp[1]);   \
        float2 f2 = __half22float2(hp[2]); float2 f3 = __half22float2(hp[3]);   \
        a[P][0] += f0.x * (V); a[P][1] += f0.y * (V);                           \
        a[P][2] += f1.x * (V); a[P][3] += f1.y * (V);                           \
        a[P][4] += f2.x * (V); a[P][5] += f2.y * (V);                           \
        a[P][6] += f3.x * (V); a[P][7] += f3.y * (V);                           \
    }

template <bool WRITE_NXT>
__global__ __launch_bounds__(256, 4)   // 4 blocks/CU guaranteed resident (VGPR<=128, LDS 0)
void gather_p5_kernel(const __half* __restrict__ emb, const int* __restrict__ slp,
                      const unsigned* __restrict__ eg, const int* __restrict__ uflag,
                      __half* __restrict__ outp, float* __restrict__ acc,
                      int* __restrict__ bar) {
    const int b = blockIdx.x;
    const int t = threadIdx.x;
    const int g = t >> 3;                        // 32 groups of 8 lanes
    const int c = (t & 7) * 8;                   // dim offset (8 dims/lane)

    float a[5][8];
    int jc[5];
    int rb[5];
    bool act[5];
#pragma unroll
    for (int p = 0; p < 5; ++p) {
        int l = g + 32 * p;
        int n = l * 1024 + b;
        bool ok = (l < NROW_B) && (n < N_NODES);
        bool need = ok && ((n >= NUM_USERS) || uflag[n]);
        act[p] = ok && (WRITE_NXT || need);
        rb[p] = n * 11;
        jc[p] = act[p] ? slp[n * 11] : 0;
#pragma unroll
        for (int i = 0; i < 8; ++i) a[p][i] = 0.f;
    }

    for (int sl = 0; sl < NSLICE; ++sl) {
#pragma unroll
        for (int p = 0; p < 5; ++p) {
            if (!act[p]) continue;
            int j = jc[p];
            int e = slp[rb[p] + sl + 1];
            for (; j + 4 <= e; j += 4) {
                unsigned w0 = eg[j], w1 = eg[j + 1], w2 = eg[j + 2], w3 = eg[j + 3];
                uint4 r0 = *reinterpret_cast<const uint4*>(emb + (long)(w0 & 0x3FFFF) * EMBED_DIM + c);
                uint4 r1 = *reinterpret_cast<const uint4*>(emb + (long)(w1 & 0x3FFFF) * EMBED_DIM + c);
                uint4 r2 = *reinterpret_cast<const uint4*>(emb + (long)(w2 & 0x3FFFF) * EMBED_DIM + c);
                uint4 r3 = *reinterpret_cast<const uint4*>(emb + (long)(w3 & 0x3FFFF) * EMBED_DIM + c);
                float v0 = ((float)(w0 >> 18) + 0.5f) * 6.103515625e-5f;
                float v1 = ((float)(w1 >> 18) + 0.5f) * 6.103515625e-5f;
                float v2 = ((float)(w2 >> 18) + 0.5f) * 6.103515625e-5f;
                float v3 = ((float)(w3 >> 18) + 0.5f) * 6.103515625e-5f;
                ACCP(p, r0, v0) ACCP(p, r1, v1) ACCP(p, r2, v2) ACCP(p, r3, v3)
            }
            int rem = e - j;
            if (rem & 2) {
                unsigned w0 = eg[j], w1 = eg[j + 1];
                uint4 r0 = *reinterpret_cast<const uint4*>(emb + (long)(w0 & 0x3FFFF) * EMBED_DIM + c);
                uint4 r1 = *reinterpret_cast<const uint4*>(emb + (long)(w1 & 0x3FFFF) * EMBED_DIM + c);
                float v0 = ((float)(w0 >> 18) + 0.5f) * 6.103515625e-5f;
                float v1 = ((float)(w1 >> 18) + 0.5f) * 6.103515625e-5f;
                ACCP(p, r0, v0) ACCP(p, r1, v1)
                j += 2;
            }
            if (rem & 1) {
                unsigned w0 = eg[j];
                uint4 r0 = *reinterpret_cast<const uint4*>(emb + (long)(w0 & 0x3FFFF) * EMBED_DIM + c);
                float v0 = ((float)(w0 >> 18) + 0.5f) * 6.103515625e-5f;
                ACCP(p, r0, v0)
            }
            jc[p] = e;
        }
        if (sl != NSLICE - 1) {
            // soft barrier (perf-only; bounded spin -> cannot hang)
            if (t == 0) {
                __hip_atomic_fetch_add(bar + sl, 1, __ATOMIC_RELAXED, __HIP_MEMORY_SCOPE_AGENT);
                int it = 0;
                while (it < 30000 &&
                       __hip_atomic_load(bar + sl, __ATOMIC_RELAXED, __HIP_MEMORY_SCOPE_AGENT) < GBLK2) {
                    __builtin_amdgcn_s_sleep(1);
                    ++it;
                }
            }
            __syncthreads();
        }
    }

#pragma unroll
    for (int p = 0; p < 5; ++p) {
        int l = g + 32 * p;
        int n = l * 1024 + b;
        if (l >= NROW_B || n >= N_NODES) continue;
        bool need = (n >= NUM_USERS) || uflag[n];
        if (WRITE_NXT) {
            uint4 o;
            __half2* op = reinterpret_cast<__half2*>(&o);
            op[0] = __float22half2_rn(make_float2(a[p][0], a[p][1]));
            op[1] = __float22half2_rn(make_float2(a[p][2], a[p][3]));
            op[2] = __float22half2_rn(make_float2(a[p][4], a[p][5]));
            op[3] = __float22half2_rn(make_float2(a[p][6], a[p][7]));
            *reinterpret_cast<uint4*>(outp + (long)n * EMBED_DIM + c) = o;
            if (need) {
                float* ap = acc + (long)n * EMBED_DIM + c;
                float4 x0 = *reinterpret_cast<float4*>(ap);
                float4 x1 = *reinterpret_cast<float4*>(ap + 4);
                x0.x += a[p][0]; x0.y += a[p][1]; x0.z += a[p][2]; x0.w += a[p][3];
                x1.x += a[p][4]; x1.y += a[p][5]; x1.z += a[p][6]; x1.w += a[p][7];
                *reinterpret_cast<float4*>(ap)     = x0;
                *reinterpret_cast<float4*>(ap + 4) = x1;
            }
        } else if (need) {
            const float* ap = acc + (long)n * EMBED_DIM + c;
            float4 x0 = *reinterpret_cast<const float4*>(ap);
            float4 x1 = *reinterpret_cast<const float4*>(ap + 4);
            uint4 o;
            __half2* op = reinterpret_cast<__half2*>(&o);
            op[0] = __float22half2_rn(make_float2(x0.x + a[p][0], x0.y + a[p][1]));
            op[1] = __float22half2_rn(make_float2(x0.z + a[p][2], x0.w + a[p][3]));
            op[2] = __float22half2_rn(make_float2(x1.x + a[p][4], x1.y + a[p][5]));
            op[3] = __float22half2_rn(make_float2(x1.z + a[p][6], x1.w + a[p][7]));
            *reinterpret_cast<uint4*>(outp + (long)n * EMBED_DIM + c) = o;
        }
    }
}

// ---------------- ratings: fp16 MFMA GEMM, A=items/B=users ------------------
// D[m=item][n=user]: C/D col(l&15)=user, row=(l>>4)*4+reg = 4 CONSECUTIVE items
// -> one f32x4 nontemporal store per fragment.
__global__ __launch_bounds__(256)
void ratings_mfma_kernel(const __half* __restrict__ T16, const int* __restrict__ users,
                         float* __restrict__ out) {
    const int w  = threadIdx.x >> 6;            // wave 0..3
    const int l  = threadIdx.x & 63;
    const int u0 = blockIdx.y * 32 + (w & 1) * 16;
    const int i0 = blockIdx.x * 128 + (w >> 1) * 64;
    const int row = l & 15;
    const int kq  = (l >> 4) * 8;
    const int uid = users[u0 + row];

    f32x4a acc0 = {0.f, 0.f, 0.f, 0.f};
    f32x4a acc1 = {0.f, 0.f, 0.f, 0.f};
    f32x4a acc2 = {0.f, 0.f, 0.f, 0.f};
    f32x4a acc3 = {0.f, 0.f, 0.f, 0.f};

    int ir0 = i0 + 0 * 16 + row; if (ir0 >= NUM_ITEMS) ir0 = NUM_ITEMS - 1;
    int ir1 = i0 + 1 * 16 + row; if (ir1 >= NUM_ITEMS) ir1 = NUM_ITEMS - 1;
    int ir2 = i0 + 2 * 16 + row; if (ir2 >= NUM_ITEMS) ir2 = NUM_ITEMS - 1;
    int ir3 = i0 + 3 * 16 + row; if (ir3 >= NUM_ITEMS) ir3 = NUM_ITEMS - 1;

#pragma unroll
    for (int ks = 0; ks < EMBED_DIM; ks += 32) {
        f16x8 bu = *reinterpret_cast<const f16x8*>(T16 + (long)uid * EMBED_DIM + ks + kq);
        f16x8 a0 = *reinterpret_cast<const f16x8*>(T16 + (long)(NUM_USERS + ir0) * EMBED_DIM + ks + kq);
        f16x8 a1 = *reinterpret_cast<const f16x8*>(T16 + (long)(NUM_USERS + ir1) * EMBED_DIM + ks + kq);
        f16x8 a2 = *reinterpret_cast<const f16x8*>(T16 + (long)(NUM_USERS + ir2) * EMBED_DIM + ks + kq);
        f16x8 a3 = *reinterpret_cast<const f16x8*>(T16 + (long)(NUM_USERS + ir3) * EMBED_DIM + ks + kq);
        acc0 = __builtin_amdgcn_mfma_f32_16x16x32_f16(a0, bu, acc0, 0, 0, 0);
        acc1 = __builtin_amdgcn_mfma_f32_16x16x32_f16(a1, bu, acc1, 0, 0, 0);
        acc2 = __builtin_amdgcn_mfma_f32_16x16x32_f16(a2, bu, acc2, 0, 0, 0);
        acc3 = __builtin_amdgcn_mfma_f32_16x16x32_f16(a3, bu, acc3, 0, 0, 0);
    }

    const float inv = 1.0f / 16.0f;              // (acc/4)·(acc/4) = acc·acc/16
    const int ucol = u0 + (l & 15);
    const int itb  = (l >> 4) * 4;
    long obase = (long)ucol * NUM_ITEMS;
#define STORE_FRAG(ACC, C)                                                      \
    {                                                                           \
        int it0 = i0 + (C) * 16 + itb;                                          \
        if (it0 < NUM_ITEMS) {                                                  \
            f32x4 v = {ACC[0] * inv, ACC[1] * inv, ACC[2] * inv, ACC[3] * inv}; \
            __builtin_nontemporal_store(v, reinterpret_cast<f32x4*>(out + obase + it0)); \
        }                                                                       \
    }
    STORE_FRAG(acc0, 0)
    STORE_FRAG(acc1, 1)
    STORE_FRAG(acc2, 2)
    STORE_FRAG(acc3, 3)
#undef STORE_FRAG
}

extern "C" void kernel_launch(void* const* d_in, const int* in_sizes, int n_in,
                              void* d_out, int out_size, void* d_ws, size_t ws_size,
                              hipStream_t stream) {
    const float* ue    = (const float*)d_in[0];
    const float* ie    = (const float*)d_in[1];
    const float* val   = (const float*)d_in[2];
    const int*   src   = (const int*)d_in[3];
    const int*   dst   = (const int*)d_in[4];
    const int*   users = (const int*)d_in[5];
    float* out = (float*)d_out;

    // ws: acc fp32 (38.4 MB) + two fp16 tables (19.2 MB each) + uflag (400 KB)
    const size_t tab = (size_t)N_NODES * EMBED_DIM;
    float*  acc   = (float*)d_ws;
    __half* h0    = (__half*)(acc + tab);
    __half* h1    = h0 + tab;
    int*    uflag = (int*)(h1 + tab);

    // CSR scratch lives in d_out (ratings overwrites all of it at the end)
    char* ob = (char*)d_out;
    unsigned* edge_s  = (unsigned*)(ob);                 // [0,16MB)   final 4B edges
    int2* tmp         = (int2*)(ob + (64u << 20));       // [64,96MB)  bucket-partitioned
    int*  hist        = (int*) (ob + (96u << 20));       // 489*1024*4 = 2.0 MB
    int*  off         = (int*) (ob + (98u << 20));       // 2.0 MB
    int*  bucketTotal = (int*) (ob + (101u << 20));      // 4 KB
    int*  bucketBase  = (int*) (ob + (102u << 20));      // 4 KB + 4
    int*  slp         = (int*) (ob + (104u << 20));      // 150000*11*4 = 6.6 MB
    int*  bar         = (int*) (ob + (112u << 20));      // 64 ints (soft barrier)

    clear_uflag_kernel<<<(NUM_USERS + 255) / 256, 256, 0, stream>>>(uflag, bar);
    mark_users_kernel<<<(BATCH + 255) / 256, 256, 0, stream>>>(users, uflag);

    const int totalv = N_NODES * EMBED_DIM / 4;
    init_emb_kernel<<<(totalv + 255) / 256, 256, 0, stream>>>(ue, ie, uflag, acc, (__half2*)h0);

    // ---- CSR build: 1024 buckets, local-major slice-segmented rows, slp ----
    histA_kernel <<<NBLK_A, 256, 0, stream>>>(src, hist);
    scanA_kernel <<<NBKT2, 512, 0, stream>>>(hist, off, bucketTotal);
    scanB2_kernel<<<1, 512, 0, stream>>>(bucketTotal, bucketBase);
    partA3_kernel<<<NBLK_A, 256, 0, stream>>>(src, dst, val, off, bucketBase, tmp);
    passB2_kernel<<<NBKT2, 512, 0, stream>>>(tmp, bucketBase, slp, edge_s);

    // ---- 3 propagation layers (persistent, slice-synced, deep-ILP) ----
    gather_p5_kernel<true ><<<GBLK2, 256, 0, stream>>>(h0, slp, edge_s, uflag, h1, acc, bar);
    gather_p5_kernel<true ><<<GBLK2, 256, 0, stream>>>(h1, slp, edge_s, uflag, h0, acc, bar + 16);
    gather_p5_kernel<false><<<GBLK2, 256, 0, stream>>>(h0, slp, edge_s, uflag, h1, acc, bar + 32);

    // ---- ratings GEMM straight from T16 (= h1, written by layer 3) ----
    dim3 rgrid((NUM_ITEMS + 127) / 128, BATCH / 32);
    ratings_mfma_kernel<<<rgrid, 256, 0, stream>>>(h1, users, out);
}